// Round 2
// baseline (105.855 us; speedup 1.0000x reference)
//
#include <hip/hip_runtime.h>
#include <hip/hip_bf16.h>

#define M_SAMP 4096
#define D_IN   100
#define HID    256
#define IN_DIM 101
#define NSQ    10000   // 100*100
#define NPAD   10112   // 79*128, padded rows of P

typedef __attribute__((ext_vector_type(8))) short short8;
typedef __attribute__((ext_vector_type(4))) float f32x4;

// async global->LDS, 16B per lane; dst must be wave-uniform (HW adds lane*16)
__device__ __forceinline__ void gload_lds16(const void* g, void* l) {
    __builtin_amdgcn_global_load_lds(
        (const __attribute__((address_space(1))) void*)g,
        (__attribute__((address_space(3))) void*)l, 16, 0, 0);
}

// ---------------- kernel 1: W1T[j][h] = W1[h][j] ----------------
__global__ __launch_bounds__(256) void k_w1t(const float* __restrict__ W1,
                                             float* __restrict__ W1T) {
    int j = blockIdx.x;   // 0..100
    int h = threadIdx.x;  // 0..255
    W1T[j * HID + h] = W1[h * IN_DIM + j];
}

// ---------------- kernel 2: forward + grad (fp32), S2n (bf16) ----------------
__global__ __launch_bounds__(256) void k_fwd(
        const float* __restrict__ t, const float* __restrict__ X,
        const float* __restrict__ W1, const float* __restrict__ W1T,
        const float* __restrict__ b1, const float* __restrict__ W2,
        const float* __restrict__ b2,
        float* __restrict__ u_out, float* __restrict__ dux_out,
        float* __restrict__ dut_out, __hip_bfloat16* __restrict__ S2n) {
    const int SM = 8;
    __shared__ float s_in[SM][IN_DIM];
    __shared__ float c_sh[SM][HID];   // W2_h * cos(z)
    __shared__ float us_sh[SM][HID];  // W2_h * sin(z)

    int i0 = blockIdx.x * SM;
    int tid = threadIdx.x;

    for (int idx = tid; idx < SM * IN_DIM; idx += 256) {
        int i = idx / IN_DIM, j = idx % IN_DIM;
        s_in[i][j] = (j == 0) ? t[i0 + i] : X[(size_t)(i0 + i) * D_IN + (j - 1)];
    }
    __syncthreads();

    int h = tid;
    float z[SM];
    float bb = b1[h];
#pragma unroll
    for (int i = 0; i < SM; i++) z[i] = bb;
    for (int j = 0; j < IN_DIM; j++) {
        float w = W1T[j * HID + h];   // coalesced across lanes
#pragma unroll
        for (int i = 0; i < SM; i++) z[i] += w * s_in[i][j];
    }
    float w2 = W2[h];
#pragma unroll
    for (int i = 0; i < SM; i++) {
        float sz, cz;
        sincosf(z[i], &sz, &cz);
        c_sh[i][h] = w2 * cz;
        us_sh[i][h] = w2 * sz;
        S2n[(size_t)(i0 + i) * HID + h] = __float2bfloat16(-w2 * sz);
    }
    __syncthreads();

    for (int off = 128; off > 0; off >>= 1) {
        if (tid < off) {
#pragma unroll
            for (int i = 0; i < SM; i++) us_sh[i][tid] += us_sh[i][tid + off];
        }
        __syncthreads();
    }
    if (tid < SM) u_out[i0 + tid] = us_sh[tid][0] + b2[0];

    if (tid < IN_DIM) {
        float acc[SM];
#pragma unroll
        for (int i = 0; i < SM; i++) acc[i] = 0.f;
        for (int hh = 0; hh < HID; hh++) {
            float w = W1[hh * IN_DIM + tid];  // coalesced across lanes
#pragma unroll
            for (int i = 0; i < SM; i++) acc[i] += c_sh[i][hh] * w;
        }
        if (tid == 0) {
            for (int i = 0; i < SM; i++) dut_out[i0 + i] = acc[i];
        } else {
            for (int i = 0; i < SM; i++)
                dux_out[(size_t)(i0 + i) * D_IN + (tid - 1)] = acc[i];
        }
    }
}

// ---------------- kernel 3: P[n][h] = W1x[h][j]*W1x[h][k], bf16, padded ----------------
// 16 rows per block -> 632 blocks (vs 10000 trivial blocks before)
__global__ __launch_bounds__(256) void k_pgen(const float* __restrict__ W1T,
                                              __hip_bfloat16* __restrict__ P) {
    int n0 = blockIdx.x * 16;
    int h = threadIdx.x;
#pragma unroll
    for (int nl = 0; nl < 16; nl++) {
        int n = n0 + nl;
        float v = 0.f;
        if (n < NSQ) {
            int j = n / D_IN, k = n - j * D_IN;
            v = W1T[(1 + j) * HID + h] * W1T[(1 + k) * HID + h];
        }
        P[(size_t)n * HID + h] = __float2bfloat16(v);
    }
}

// ---------------- kernel 4: C[4096][10000] = S2n @ P^T (MFMA bf16, m97-style) ----------------
#define BM 128
#define BN 128
#define BK 64
#define NK 4      // 256 / 64
#define NBLK 79   // NPAD / 128

__global__ __launch_bounds__(256) void k_gemm(
        const __hip_bfloat16* __restrict__ A,   // [4096][256] row-major
        const __hip_bfloat16* __restrict__ B,   // [NPAD][256] n-major (=B^T)
        float* __restrict__ C) {                // [4096][10000]
    // linear LDS [128 rows][64 cols] bf16 = 128B/row; double-buffered
    __shared__ __hip_bfloat16 As[2][BM * BK];   // 2 x 16 KB
    __shared__ __hip_bfloat16 Bs[2][BM * BK];   // 2 x 16 KB

    int bid = blockIdx.x;
    int bm = bid / NBLK, bn = bid % NBLK;
    int m0 = bm * BM, n0 = bn * BN;
    int tid = threadIdx.x;
    int lane = tid & 63, wave = tid >> 6;
    int wm = wave >> 1, wn = wave & 1;   // 2x2 waves, 64x64 out each

    // staging geometry: wave w covers rows w*32 .. w*32+31 (4 loads x 8 rows),
    // lane l -> row +(l>>3), byte in row (l&7)*16  (matches lds base + lane*16)
    int srow = wave * 32 + (lane >> 3);
    int scol = (lane & 7) * 8;           // bf16 elements within row

    f32x4 acc[4][4];
#pragma unroll
    for (int i = 0; i < 4; i++)
#pragma unroll
        for (int j = 0; j < 4; j++) acc[i][j] = {0.f, 0.f, 0.f, 0.f};

    // ---- stage kt=0 into buf 0 ----
#pragma unroll
    for (int i = 0; i < 4; i++) {
        gload_lds16(A + (size_t)(m0 + srow + i * 8) * HID + scol,
                    &As[0][(wave * 32 + i * 8) * BK]);
        gload_lds16(B + (size_t)(n0 + srow + i * 8) * HID + scol,
                    &Bs[0][(wave * 32 + i * 8) * BK]);
    }

    for (int kt = 0; kt < NK; kt++) {
        int cur = kt & 1;
        if (kt + 1 < NK) {
            int nxt = cur ^ 1;
            int kc = (kt + 1) * BK;
#pragma unroll
            for (int i = 0; i < 4; i++) {
                gload_lds16(A + (size_t)(m0 + srow + i * 8) * HID + kc + scol,
                            &As[nxt][(wave * 32 + i * 8) * BK]);
                gload_lds16(B + (size_t)(n0 + srow + i * 8) * HID + kc + scol,
                            &Bs[nxt][(wave * 32 + i * 8) * BK]);
            }
        }
        __syncthreads();   // drains vmcnt -> buf[cur] ready

        const char* Ab = (const char*)As[cur];
        const char* Bb = (const char*)Bs[cur];
        int lo = lane & 15, hi16 = (lane >> 4) << 4;   // byte offset of k-group
#pragma unroll
        for (int kk = 0; kk < 2; kk++) {
            short8 af[4], bf4[4];
#pragma unroll
            for (int mi = 0; mi < 4; mi++) {
                int r = wm * 64 + mi * 16 + lo;
                af[mi] = *(const short8*)(Ab + r * 128 + kk * 64 + hi16);
            }
#pragma unroll
            for (int ni = 0; ni < 4; ni++) {
                int r = wn * 64 + ni * 16 + lo;
                bf4[ni] = *(const short8*)(Bb + r * 128 + kk * 64 + hi16);
            }
#pragma unroll
            for (int mi = 0; mi < 4; mi++)
#pragma unroll
                for (int ni = 0; ni < 4; ni++)
                    acc[mi][ni] = __builtin_amdgcn_mfma_f32_16x16x32_bf16(
                        af[mi], bf4[ni], acc[mi][ni], 0, 0, 0);
        }
        __syncthreads();   // readers done before next stage overwrites buf[cur^1]
    }

    // epilogue: row = m0+wm*64+mi*16+(lane>>4)*4+r, col = n0+wn*64+ni*16+(lane&15)
#pragma unroll
    for (int mi = 0; mi < 4; mi++) {
        int rbase = m0 + wm * 64 + mi * 16 + ((lane >> 4) << 2);
#pragma unroll
        for (int ni = 0; ni < 4; ni++) {
            int col = n0 + wn * 64 + ni * 16 + (lane & 15);
            if (col < NSQ) {
#pragma unroll
                for (int r = 0; r < 4; r++)
                    C[(size_t)(rbase + r) * NSQ + col] = acc[mi][ni][r];
            }
        }
    }
}

extern "C" void kernel_launch(void* const* d_in, const int* in_sizes, int n_in,
                              void* d_out, int out_size, void* d_ws, size_t ws_size,
                              hipStream_t stream) {
    const float* t  = (const float*)d_in[0];
    const float* X  = (const float*)d_in[1];
    const float* W1 = (const float*)d_in[2];
    const float* b1 = (const float*)d_in[3];
    const float* W2 = (const float*)d_in[4];
    const float* b2 = (const float*)d_in[5];

    float* out = (float*)d_out;
    float* u_out = out;                                  // 4096
    float* dux   = out + M_SAMP;                         // 409600
    float* dut   = out + M_SAMP + (size_t)M_SAMP * D_IN; // 4096
    float* H     = dut + M_SAMP;                         // 40,960,000

    char* ws = (char*)d_ws;
    float* W1T          = (float*)ws;                               // 103,424 B
    __hip_bfloat16* S2n = (__hip_bfloat16*)(ws + 131072);           // 2 MB
    __hip_bfloat16* P   = (__hip_bfloat16*)(ws + 131072 + 2097152); // 5.06 MB (padded)

    k_w1t<<<IN_DIM, 256, 0, stream>>>(W1, W1T);
    k_fwd<<<M_SAMP / 8, 256, 0, stream>>>(t, X, W1, W1T, b1, W2, b2,
                                          u_out, dux, dut, S2n);
    k_pgen<<<NPAD / 16, 256, 0, stream>>>(W1T, P);
    k_gemm<<<(M_SAMP / BM) * NBLK, 256, 0, stream>>>(S2n, P, H);
}

// Round 3
// 103.544 us; speedup vs baseline: 1.0223x; 1.0223x over previous
//
#include <hip/hip_runtime.h>
#include <hip/hip_bf16.h>

#define M_SAMP 4096
#define D_IN   100
#define HID    256
#define IN_DIM 101
#define NSQ    10000   // 100*100
#define NPAD   10112   // 79*128, padded rows of P

typedef __attribute__((ext_vector_type(8))) short short8;
typedef __attribute__((ext_vector_type(4))) float f32x4;

// async global->LDS, 16B per lane; LDS dst wave-uniform (HW adds lane*16),
// global src per-lane.
__device__ __forceinline__ void gload_lds16(const void* g, void* l) {
    __builtin_amdgcn_global_load_lds(
        (const __attribute__((address_space(1))) void*)g,
        (__attribute__((address_space(3))) void*)l, 16, 0, 0);
}

// ---------------- kernel 1: W1T[j][h] = W1[h][j] ----------------
__global__ __launch_bounds__(256) void k_w1t(const float* __restrict__ W1,
                                             float* __restrict__ W1T) {
    int j = blockIdx.x;   // 0..100
    int h = threadIdx.x;  // 0..255
    W1T[j * HID + h] = W1[h * IN_DIM + j];
}

// ---------------- kernel 2: forward + grad (fp32), S2n (bf16) ----------------
__global__ __launch_bounds__(256) void k_fwd(
        const float* __restrict__ t, const float* __restrict__ X,
        const float* __restrict__ W1, const float* __restrict__ W1T,
        const float* __restrict__ b1, const float* __restrict__ W2,
        const float* __restrict__ b2,
        float* __restrict__ u_out, float* __restrict__ dux_out,
        float* __restrict__ dut_out, __hip_bfloat16* __restrict__ S2n) {
    const int SM = 8;
    __shared__ float s_in[SM][IN_DIM];
    __shared__ float c_sh[SM][HID];   // W2_h * cos(z)
    __shared__ float us_sh[SM][HID];  // W2_h * sin(z)

    int i0 = blockIdx.x * SM;
    int tid = threadIdx.x;

    for (int idx = tid; idx < SM * IN_DIM; idx += 256) {
        int i = idx / IN_DIM, j = idx % IN_DIM;
        s_in[i][j] = (j == 0) ? t[i0 + i] : X[(size_t)(i0 + i) * D_IN + (j - 1)];
    }
    __syncthreads();

    int h = tid;
    float z[SM];
    float bb = b1[h];
#pragma unroll
    for (int i = 0; i < SM; i++) z[i] = bb;
    for (int j = 0; j < IN_DIM; j++) {
        float w = W1T[j * HID + h];   // coalesced across lanes
#pragma unroll
        for (int i = 0; i < SM; i++) z[i] += w * s_in[i][j];
    }
    float w2 = W2[h];
#pragma unroll
    for (int i = 0; i < SM; i++) {
        float sz, cz;
        sincosf(z[i], &sz, &cz);
        c_sh[i][h] = w2 * cz;
        us_sh[i][h] = w2 * sz;
        S2n[(size_t)(i0 + i) * HID + h] = __float2bfloat16(-w2 * sz);
    }
    __syncthreads();

    for (int off = 128; off > 0; off >>= 1) {
        if (tid < off) {
#pragma unroll
            for (int i = 0; i < SM; i++) us_sh[i][tid] += us_sh[i][tid + off];
        }
        __syncthreads();
    }
    if (tid < SM) u_out[i0 + tid] = us_sh[tid][0] + b2[0];

    if (tid < IN_DIM) {
        float acc[SM];
#pragma unroll
        for (int i = 0; i < SM; i++) acc[i] = 0.f;
        for (int hh = 0; hh < HID; hh++) {
            float w = W1[hh * IN_DIM + tid];  // coalesced across lanes
#pragma unroll
            for (int i = 0; i < SM; i++) acc[i] += c_sh[i][hh] * w;
        }
        if (tid == 0) {
            for (int i = 0; i < SM; i++) dut_out[i0 + i] = acc[i];
        } else {
            for (int i = 0; i < SM; i++)
                dux_out[(size_t)(i0 + i) * D_IN + (tid - 1)] = acc[i];
        }
    }
}

// ---------------- kernel 3: P[n][h] = W1x[h][j]*W1x[h][k], bf16, padded ----------------
__global__ __launch_bounds__(256) void k_pgen(const float* __restrict__ W1T,
                                              __hip_bfloat16* __restrict__ P) {
    int n0 = blockIdx.x * 16;
    int h = threadIdx.x;
#pragma unroll
    for (int nl = 0; nl < 16; nl++) {
        int n = n0 + nl;
        float v = 0.f;
        if (n < NSQ) {
            int j = n / D_IN, k = n - j * D_IN;
            v = W1T[(1 + j) * HID + h] * W1T[(1 + k) * HID + h];
        }
        P[(size_t)n * HID + h] = __float2bfloat16(v);
    }
}

// ---------------- kernel 4: C[4096][10000] = S2n @ P^T (MFMA bf16) ----------------
// Both-sides XOR swizzle: LDS dest linear (global_load_lds constraint),
// global SOURCE pre-permuted with byte ^= ((row&7)<<4), READ applies same XOR.
#define BM 128
#define BN 128
#define BK 64
#define NK 4      // 256 / 64
#define NBLK 79   // NPAD / 128

__global__ __launch_bounds__(256) void k_gemm(
        const __hip_bfloat16* __restrict__ A,   // [4096][256] row-major
        const __hip_bfloat16* __restrict__ B,   // [NPAD][256] n-major (=B^T)
        float* __restrict__ C) {                // [4096][10000]
    __shared__ __hip_bfloat16 As[2][BM * BK];   // 2 x 16 KB
    __shared__ __hip_bfloat16 Bs[2][BM * BK];   // 2 x 16 KB

    int bid = blockIdx.x;
    int bm = bid / NBLK, bn = bid % NBLK;
    int m0 = bm * BM, n0 = bn * BN;
    int tid = threadIdx.x;
    int lane = tid & 63, wave = tid >> 6;
    int wm = wave >> 1, wn = wave & 1;   // 2x2 waves, 64x64 out each

    // staging: wave w covers 32 rows (4 x 8); lane -> row +(l>>3).
    // source col pre-swizzled so linear LDS write == swizzled layout:
    int srow8 = lane >> 3;                      // row within 8-row group (= r&7)
    int scol = ((lane & 7) ^ srow8) * 8;        // bf16 elems; = c' ^ ((r&7)<<4) in bytes

    f32x4 acc[4][4];
#pragma unroll
    for (int i = 0; i < 4; i++)
#pragma unroll
        for (int j = 0; j < 4; j++) acc[i][j] = {0.f, 0.f, 0.f, 0.f};

    auto stage = [&](int buf, int kt) {
        int kc = kt * BK;
#pragma unroll
        for (int i = 0; i < 4; i++) {
            int rbase = wave * 32 + i * 8;
            gload_lds16(A + (size_t)(m0 + rbase + srow8) * HID + kc + scol,
                        &As[buf][rbase * BK]);
            gload_lds16(B + (size_t)(n0 + rbase + srow8) * HID + kc + scol,
                        &Bs[buf][rbase * BK]);
        }
    };

    stage(0, 0);

    for (int kt = 0; kt < NK; kt++) {
        int cur = kt & 1;
        __syncthreads();                 // vmcnt(0) drain: buf[cur] ready;
                                         // also: all waves done reading buf[cur^1]
        if (kt + 1 < NK) stage(cur ^ 1, kt + 1);   // prefetch hides under compute

        const char* Ab = (const char*)As[cur];
        const char* Bb = (const char*)Bs[cur];
        int lo = lane & 15;
        int xr = (lane & 7) << 4;        // row-XOR term (r&7 == lane&7 here)
#pragma unroll
        for (int kk = 0; kk < 2; kk++) {
            int kbs = (kk * 64 + ((lane >> 4) << 4)) ^ xr;   // swizzled byte-in-row
            short8 af[4], bf4[4];
#pragma unroll
            for (int mi = 0; mi < 4; mi++) {
                int r = wm * 64 + mi * 16 + lo;
                af[mi] = *(const short8*)(Ab + r * 128 + kbs);
            }
#pragma unroll
            for (int ni = 0; ni < 4; ni++) {
                int r = wn * 64 + ni * 16 + lo;
                bf4[ni] = *(const short8*)(Bb + r * 128 + kbs);
            }
#pragma unroll
            for (int mi = 0; mi < 4; mi++)
#pragma unroll
                for (int ni = 0; ni < 4; ni++)
                    acc[mi][ni] = __builtin_amdgcn_mfma_f32_16x16x32_bf16(
                        af[mi], bf4[ni], acc[mi][ni], 0, 0, 0);
        }
    }

    // epilogue: row = m0+wm*64+mi*16+(lane>>4)*4+r, col = n0+wn*64+ni*16+(lane&15)
#pragma unroll
    for (int mi = 0; mi < 4; mi++) {
        int rbase = m0 + wm * 64 + mi * 16 + ((lane >> 4) << 2);
#pragma unroll
        for (int ni = 0; ni < 4; ni++) {
            int col = n0 + wn * 64 + ni * 16 + (lane & 15);
            if (col < NSQ) {
#pragma unroll
                for (int r = 0; r < 4; r++)
                    C[(size_t)(rbase + r) * NSQ + col] = acc[mi][ni][r];
            }
        }
    }
}

extern "C" void kernel_launch(void* const* d_in, const int* in_sizes, int n_in,
                              void* d_out, int out_size, void* d_ws, size_t ws_size,
                              hipStream_t stream) {
    const float* t  = (const float*)d_in[0];
    const float* X  = (const float*)d_in[1];
    const float* W1 = (const float*)d_in[2];
    const float* b1 = (const float*)d_in[3];
    const float* W2 = (const float*)d_in[4];
    const float* b2 = (const float*)d_in[5];

    float* out = (float*)d_out;
    float* u_out = out;                                  // 4096
    float* dux   = out + M_SAMP;                         // 409600
    float* dut   = out + M_SAMP + (size_t)M_SAMP * D_IN; // 4096
    float* H     = dut + M_SAMP;                         // 40,960,000

    char* ws = (char*)d_ws;
    float* W1T          = (float*)ws;                               // 103,424 B
    __hip_bfloat16* S2n = (__hip_bfloat16*)(ws + 131072);           // 2 MB
    __hip_bfloat16* P   = (__hip_bfloat16*)(ws + 131072 + 2097152); // 5.18 MB (padded)

    k_w1t<<<IN_DIM, 256, 0, stream>>>(W1, W1T);
    k_fwd<<<M_SAMP / 8, 256, 0, stream>>>(t, X, W1, W1T, b1, W2, b2,
                                          u_out, dux, dut, S2n);
    k_pgen<<<NPAD / 16, 256, 0, stream>>>(W1T, P);
    k_gemm<<<(M_SAMP / BM) * NBLK, 256, 0, stream>>>(S2n, P, H);
}